// Round 13
// baseline (145.846 us; speedup 1.0000x reference)
//
#include <hip/hip_runtime.h>
#include <hip/hip_bf16.h>

namespace {
constexpr int NB = 128;   // batch
constexpr int NL = 2048;  // seq len
constexpr int ND = 128;   // emb dim
constexpr int NH = 256;   // hidden
constexpr int NO = 128;   // encoder out dim
constexpr int NK = 64;    // top-k
constexpr int MCAP = 192; // candidate cap per batch
constexpr int HTHR = 96;  // histogram cumulative threshold
constexpr int BLOOP = 8;  // batches per score block
constexpr float MASK_FILL_F = -1e9f;
constexpr float LN_EPS_F = 1e-5f;
}

typedef __attribute__((ext_vector_type(8))) short bf16x8;
typedef __attribute__((ext_vector_type(4))) float f32x4;

__device__ __forceinline__ unsigned short bf16rne(float x) {
  unsigned u = __float_as_uint(x);
  return (unsigned short)((u + 0x7FFFu + ((u >> 16) & 1u)) >> 16);
}

// ---------- fused prep: W1aT | P | T | We1T | We2T ----------
__global__ __launch_bounds__(256) void k_prep(
    const float* __restrict__ W1, const float* __restrict__ pos,
    const float* __restrict__ tgt, const float* __restrict__ b1,
    const float* __restrict__ We1, const float* __restrict__ We2,
    unsigned short* __restrict__ W1aT, float* __restrict__ P,
    float* __restrict__ T, unsigned short* __restrict__ We1T,
    unsigned short* __restrict__ We2T) {
  const int blk = blockIdx.x, t = threadIdx.x;
  if (blk < ND) {  // W1aT[h][d]
    W1aT[(size_t)t * ND + blk] = bf16rne(W1[(size_t)blk * NH + t]);
    return;
  }
  if (blk >= ND + NL + NB) {
    const int b2 = blk - (ND + NL + NB);
    if (b2 < 256) {  // We1T[h][d]
      We1T[(size_t)t * 256 + b2] = bf16rne(We1[(size_t)b2 * NH + t]);
    } else {         // We2T[o][d]
      const int d = b2 - 256;
      if (t < NO) We2T[(size_t)t * 256 + d] = bf16rne(We2[(size_t)d * NO + t]);
    }
    return;
  }
  int r, w_off, add_bias;
  const float* src;
  float* out;
  if (blk < ND + NL) {
    r = blk - ND; src = pos; out = P; w_off = ND; add_bias = 1;
  } else {
    r = blk - (ND + NL); src = tgt; out = T; w_off = 2 * ND; add_bias = 0;
  }
  __shared__ float row[ND];
  if (t < ND) row[t] = src[(size_t)r * ND + t];
  __syncthreads();
  float acc = add_bias ? b1[t] : 0.0f;
#pragma unroll 8
  for (int d = 0; d < ND; ++d)
    acc = fmaf(row[d], W1[(size_t)(w_off + d) * NH + t], acc);
  out[(size_t)r * NH + t] = acc;
}

// ---------- approximate scores (validated config, unchanged) ----------
__global__ __launch_bounds__(512, 2) void k_scores_mfma(
    const float* __restrict__ seq, const int* __restrict__ mask,
    const unsigned short* __restrict__ W1aT, const float* __restrict__ w2,
    const float* __restrict__ b2, const float* __restrict__ b1,
    const float* __restrict__ T, float* __restrict__ scores) {
  const int l0 = blockIdx.x * 128;
  const int b0 = blockIdx.y * BLOOP;
  const int t = threadIdx.x;
  const int lane = t & 63;
  const int w = t >> 6;
  const int wh = w & 3;
  const int wl = w >> 2;
  const int lh = lane & 15;
  const int kq = lane >> 4;

  __shared__ unsigned short sSeq[2][128 * 128];
  __shared__ float sRed[4][128];

  bf16x8 a[4][4];
#pragma unroll
  for (int ks = 0; ks < 4; ++ks)
#pragma unroll
    for (int mt = 0; mt < 4; ++mt)
      a[ks][mt] = *(const bf16x8*)(
          W1aT + (size_t)(wh * 64 + mt * 16 + lh) * ND + ks * 32 + kq * 8);

  float4 wv[4], b1v[4];
#pragma unroll
  for (int mt = 0; mt < 4; ++mt) {
    wv[mt] = *(const float4*)(w2 + wh * 64 + mt * 16 + kq * 4);
    b1v[mt] = *(const float4*)(b1 + wh * 64 + mt * 16 + kq * 4);
  }
  const float b2v = b2[0];

  ushort4 pf[8];
  auto prefetch = [&](int bb) {
    const float4* g = (const float4*)(seq + ((size_t)bb * NL + l0) * ND);
#pragma unroll
    for (int i = 0; i < 8; ++i) {
      const float4 f = g[t + i * 512];
      pf[i].x = bf16rne(f.x); pf[i].y = bf16rne(f.y);
      pf[i].z = bf16rne(f.z); pf[i].w = bf16rne(f.w);
    }
  };
  auto commit = [&](unsigned short* dst) {
#pragma unroll
    for (int i = 0; i < 8; ++i) {
      const int v = t + i * 512;
      const int row = v >> 5;
      const int c8 = (v & 31) * 8;
      const int off = (row << 8) + (c8 ^ ((row & 15) << 4));
      *(ushort4*)((char*)dst + off) = pf[i];
    }
  };

  prefetch(b0);
  commit((unsigned short*)sSeq[0]);
  __syncthreads();

#pragma unroll 1
  for (int j = 0; j < BLOOP; ++j) {
    const int b = b0 + j;
    unsigned short* cSeq = (unsigned short*)sSeq[j & 1];
    unsigned short* nSeq = (unsigned short*)sSeq[(j & 1) ^ 1];

    if (j + 1 < BLOOP) prefetch(b + 1);

    float4 Tv[4];
#pragma unroll
    for (int mt = 0; mt < 4; ++mt)
      Tv[mt] = *(const float4*)(T + (size_t)b * NH + wh * 64 + mt * 16 + kq * 4);

    f32x4 acc[4][4];
#pragma unroll
    for (int mt = 0; mt < 4; ++mt)
#pragma unroll
      for (int nt = 0; nt < 4; ++nt) acc[mt][nt] = (f32x4){0.f, 0.f, 0.f, 0.f};

#pragma unroll
    for (int ks = 0; ks < 4; ++ks) {
      bf16x8 Bf[4];
#pragma unroll
      for (int nt = 0; nt < 4; ++nt) {
        const int row = wl * 64 + nt * 16 + lh;
        const int off = (row << 8) + (((ks << 6) + (kq << 4)) ^ ((row & 15) << 4));
        Bf[nt] = *(const bf16x8*)((const char*)cSeq + off);
      }
#pragma unroll
      for (int mt = 0; mt < 4; ++mt)
#pragma unroll
        for (int nt = 0; nt < 4; ++nt)
          acc[mt][nt] = __builtin_amdgcn_mfma_f32_16x16x32_bf16(
              a[ks][mt], Bf[nt], acc[mt][nt], 0, 0, 0);
    }
    __syncthreads();
    if (j + 1 < BLOOP) commit(nSeq);

    float p[4] = {0.f, 0.f, 0.f, 0.f};
#pragma unroll
    for (int mt = 0; mt < 4; ++mt) {
#pragma unroll
      for (int nt = 0; nt < 4; ++nt) {
        float z;
        z = acc[mt][nt][0] + Tv[mt].x + b1v[mt].x; p[nt] = fmaf(fmaxf(z, 0.f), wv[mt].x, p[nt]);
        z = acc[mt][nt][1] + Tv[mt].y + b1v[mt].y; p[nt] = fmaf(fmaxf(z, 0.f), wv[mt].y, p[nt]);
        z = acc[mt][nt][2] + Tv[mt].z + b1v[mt].z; p[nt] = fmaf(fmaxf(z, 0.f), wv[mt].z, p[nt]);
        z = acc[mt][nt][3] + Tv[mt].w + b1v[mt].w; p[nt] = fmaf(fmaxf(z, 0.f), wv[mt].w, p[nt]);
      }
    }
#pragma unroll
    for (int nt = 0; nt < 4; ++nt) {
      float v = p[nt];
      v += __shfl_xor(v, 16);
      v += __shfl_xor(v, 32);
      if (lane < 16) sRed[wh][wl * 64 + nt * 16 + lane] = v;
    }
    __syncthreads();
    if (t < 128) {
      const int l = l0 + t;
      float sc = sRed[0][t] + sRed[1][t] + sRed[2][t] + sRed[3][t] + b2v;
      if (mask[(size_t)b * NL + l] == 0) sc = MASK_FILL_F;
      scores[(size_t)b * NL + l] = sc;
    }
  }
}

// ---------- fused tail: topM + exact rescore + select + MFMA encoder + LN ----------
// one block per batch, 1024 threads (16 waves). ~135 KB LDS.
__global__ __launch_bounds__(1024, 4) void k_tail(
    const float* __restrict__ scores, const float* __restrict__ seq,
    const int* __restrict__ mask, const float* __restrict__ W1,
    const float* __restrict__ w2, const float* __restrict__ b2,
    const float* __restrict__ P, const float* __restrict__ T,
    const float* __restrict__ pos,
    const unsigned short* __restrict__ We1T, const float* __restrict__ be1,
    const unsigned short* __restrict__ We2T, const float* __restrict__ be2,
    const float* __restrict__ gamma, const float* __restrict__ beta,
    float* __restrict__ out) {
  const int b = blockIdx.x, t = threadIdx.x;
  const int lane = t & 63, w = t >> 6;
  const int lh = lane & 15, kq = lane >> 4;
  __shared__ float s_stage[128 * ND];   // 64 KB; phase A aliases hist
  unsigned* hist = (unsigned*)s_stage;  // 4096 uints
  __shared__ unsigned chunk[256];
  __shared__ int sB;
  __shared__ unsigned sCntHi, sCntB, sN;
  __shared__ int s_cand[MCAP];
  __shared__ float s_cs[MCAP];
  __shared__ unsigned long long s_key[MCAP];
  __shared__ int sel_l[NK];
  __shared__ float sel_v[NK];
  __shared__ int srt_l[NK];
  __shared__ float srt_v[NK];
  __shared__ float s_at[NK];
  __shared__ unsigned short s_in[64 * 256];  // 32 KB
  __shared__ unsigned short s_h1[64 * 256];  // 32 KB
  __shared__ float red[4][128];
  __shared__ float rr[4];

  // --- phase A: histogram (masked keys skipped — same-address atomic fix;
  // bit-identical: masked bin ~785 is far below the selection bin B~2048) ---
  const unsigned mkey = ~__float_as_uint(MASK_FILL_F);
  for (int i = t; i < 4096; i += 1024) hist[i] = 0;
  if (t == 0) { sCntHi = 0; sCntB = 0; }
  __syncthreads();
  unsigned key2[2];
#pragma unroll
  for (int i = 0; i < 2; ++i) {
    unsigned u = __float_as_uint(scores[(size_t)b * NL + t + i * 1024]);
    u = (u & 0x80000000u) ? ~u : (u | 0x80000000u);
    key2[i] = u;
    if (u != mkey) atomicAdd(&hist[u >> 20], 1u);
  }
  __syncthreads();
  if (t < 256) {
    unsigned s = 0;
#pragma unroll 4
    for (int j = 0; j < 16; ++j) s += hist[t * 16 + j];
    chunk[t] = s;
  }
  __syncthreads();
  if (t == 0) {
    unsigned cum = 0;
    int c = 255;
    for (; c > 0; --c) {
      if (cum + chunk[c] >= (unsigned)HTHR) break;
      cum += chunk[c];
    }
    int bin = c * 16 + 15;
    for (; bin > c * 16; --bin) {
      if (cum + hist[bin] >= (unsigned)HTHR) break;
      cum += hist[bin];
    }
    sB = bin;
  }
  __syncthreads();
  const unsigned B = (unsigned)sB;
#pragma unroll
  for (int i = 0; i < 2; ++i) {
    if (key2[i] != mkey && (key2[i] >> 20) > B) {
      unsigned pos_ = atomicAdd(&sCntHi, 1u);
      s_cand[pos_] = t + i * 1024;
    }
  }
  __syncthreads();
  const unsigned hi = sCntHi;
#pragma unroll
  for (int i = 0; i < 2; ++i) {
    if (key2[i] != mkey && (key2[i] >> 20) == B) {
      unsigned pos_ = atomicAdd(&sCntB, 1u);
      if (hi + pos_ < (unsigned)MCAP) s_cand[hi + pos_] = t + i * 1024;
    }
  }
  __syncthreads();
  if (t == 0) {
    unsigned n = sCntHi + sCntB;
    sN = (n < (unsigned)MCAP) ? n : (unsigned)MCAP;
  }
  __syncthreads();
  const int n = (int)sN;

  // --- phase B: exact fp32 rescore, 128 rows/pass staged in LDS ---
  {
    const int hg = lane;
    const int rg = w;
    const float4* Wp = (const float4*)W1;
    const float4 wvq = ((const float4*)w2)[hg];
    const float4 Tvq = ((const float4*)(T + (size_t)b * NH))[hg];
    const float b2v = b2[0];
#pragma unroll 1
    for (int pass = 0; pass < 2; ++pass) {
      const int base = pass * 128;
      if (base >= n) break;
      __syncthreads();
#pragma unroll
      for (int i = 0; i < 4; ++i) {
        const int v = t + i * 1024;
        const int r = v >> 5, c = v & 31;
        const int slot = base + r;
        const int l = (slot < n) ? s_cand[slot] : 0;
        ((float4*)s_stage)[r * 32 + c] =
            ((const float4*)(seq + ((size_t)b * NL + l) * ND))[c];
      }
      __syncthreads();

      float acc[8][4];
#pragma unroll
      for (int r = 0; r < 8; ++r)
#pragma unroll
        for (int j = 0; j < 4; ++j) acc[r][j] = 0.0f;

      for (int d0 = 0; d0 < ND; d0 += 4) {
        float4 wq[4];
#pragma unroll
        for (int j = 0; j < 4; ++j) wq[j] = Wp[(size_t)(d0 + j) * (NH / 4) + hg];
#pragma unroll
        for (int r = 0; r < 8; ++r) {
          const float4 s = *(const float4*)&s_stage[(rg * 8 + r) * ND + d0];
          const float sv[4] = {s.x, s.y, s.z, s.w};
#pragma unroll
          for (int j = 0; j < 4; ++j) {
            acc[r][0] = fmaf(sv[j], wq[j].x, acc[r][0]);
            acc[r][1] = fmaf(sv[j], wq[j].y, acc[r][1]);
            acc[r][2] = fmaf(sv[j], wq[j].z, acc[r][2]);
            acc[r][3] = fmaf(sv[j], wq[j].w, acc[r][3]);
          }
        }
      }

#pragma unroll
      for (int r = 0; r < 8; ++r) {
        const int slot = base + rg * 8 + r;
        const int l = (slot < n) ? s_cand[slot] : 0;
        const float4 Pv = ((const float4*)(P + (size_t)l * NH))[hg];
        float z, p = 0.0f;
        z = acc[r][0] + Pv.x + Tvq.x; p = fmaf(fmaxf(z, 0.0f), wvq.x, p);
        z = acc[r][1] + Pv.y + Tvq.y; p = fmaf(fmaxf(z, 0.0f), wvq.y, p);
        z = acc[r][2] + Pv.z + Tvq.z; p = fmaf(fmaxf(z, 0.0f), wvq.z, p);
        z = acc[r][3] + Pv.w + Tvq.w; p = fmaf(fmaxf(z, 0.0f), wvq.w, p);
#pragma unroll
        for (int off = 32; off >= 1; off >>= 1) p += __shfl_xor(p, off);
        if (hg == 0 && slot < n) {
          float sc = p + b2v;
          if (mask[(size_t)b * NL + l] == 0) sc = MASK_FILL_F;
          s_cs[slot] = sc;
        }
      }
    }
  }
  __syncthreads();

  // --- phase C: rank-based exact top-64, index-sort, softmax (to LDS) ---
  for (int s = t; s < MCAP; s += 1024) {
    unsigned long long kk = 0ull;
    if (s < n) {
      unsigned u = __float_as_uint(s_cs[s]);
      u = (u & 0x80000000u) ? ~u : (u | 0x80000000u);
      const int l = s_cand[s];
      kk = ((unsigned long long)u << 11) | (unsigned long long)(NL - 1 - l);
    }
    s_key[s] = kk;
  }
  __syncthreads();
  for (int s = t; s < MCAP; s += 1024) {
    if (s < n) {
      const unsigned long long mk = s_key[s];
      int rank = 0;
      for (int j = 0; j < n; ++j) rank += (s_key[j] > mk) ? 1 : 0;
      if (rank < NK) {
        sel_l[rank] = (NL - 1) - (int)(mk & 0x7FFull);
        sel_v[rank] = s_cs[s];
      }
    }
  }
  __syncthreads();
  if (t < NK) {
    const int myl = sel_l[t];
    int pos_ = 0;
#pragma unroll 8
    for (int j = 0; j < NK; ++j) pos_ += (sel_l[j] < myl) ? 1 : 0;
    srt_l[pos_] = myl;
    srt_v[pos_] = sel_v[t];
  }
  __syncthreads();
  if (t < 64) {
    const float sc = srt_v[t];
    float m = sc;
#pragma unroll
    for (int off = 32; off >= 1; off >>= 1) m = fmaxf(m, __shfl_xor(m, off));
    const float e = expf(sc - m);
    float s = e;
#pragma unroll
    for (int off = 32; off >= 1; off >>= 1) s += __shfl_xor(s, off);
    s_at[t] = e / s;
  }
  __syncthreads();

  // --- gather [seq|pos] selected rows -> bf16 swizzled LDS ---
#pragma unroll
  for (int i = 0; i < 4; ++i) {
    const int v = t + i * 1024;  // 4096 ushort4
    const int row = v >> 6;      // 64 ushort4 per 512B row
    const int q = v & 63;
    const int idx = srt_l[row];
    float4 f;
    if (q < 32) f = ((const float4*)(seq + ((size_t)b * NL + idx) * ND))[q];
    else        f = ((const float4*)(pos + (size_t)idx * ND))[q - 32];
    ushort4 hv;
    hv.x = bf16rne(f.x); hv.y = bf16rne(f.y);
    hv.z = bf16rne(f.z); hv.w = bf16rne(f.w);
    const int off = (row << 9) + ((q * 8) ^ ((row & 15) << 4));
    *(ushort4*)((char*)s_in + off) = hv;
  }
  __syncthreads();

  // --- MFMA1: 16 waves, wave (wh=w&3, wn=w>>2) owns 64h x 16rows ---
  {
    const int wh = w & 3, wn = w >> 2;
    const int row = wn * 16 + lh;
    f32x4 acc1[4];
#pragma unroll
    for (int mt = 0; mt < 4; ++mt) acc1[mt] = (f32x4){0.f, 0.f, 0.f, 0.f};
#pragma unroll
    for (int ks = 0; ks < 8; ++ks) {
      const int off = (row << 9) + ((ks * 64 + kq * 16) ^ ((row & 15) << 4));
      const bf16x8 Bf = *(const bf16x8*)((const char*)s_in + off);
#pragma unroll
      for (int mt = 0; mt < 4; ++mt) {
        const bf16x8 Af = *(const bf16x8*)(
            We1T + (size_t)(wh * 64 + mt * 16 + lh) * 256 + ks * 32 + kq * 8);
        acc1[mt] = __builtin_amdgcn_mfma_f32_16x16x32_bf16(Af, Bf, acc1[mt], 0, 0, 0);
      }
    }
#pragma unroll
    for (int mt = 0; mt < 4; ++mt) {
      const int h0 = wh * 64 + mt * 16 + kq * 4;
      const float4 bv = *(const float4*)(be1 + h0);
      const float z0 = fmaxf(acc1[mt][0] + bv.x, 0.0f);
      const float z1 = fmaxf(acc1[mt][1] + bv.y, 0.0f);
      const float z2 = fmaxf(acc1[mt][2] + bv.z, 0.0f);
      const float z3 = fmaxf(acc1[mt][3] + bv.w, 0.0f);
      const unsigned u0 = (unsigned)bf16rne(z0) | ((unsigned)bf16rne(z1) << 16);
      const unsigned u1 = (unsigned)bf16rne(z2) | ((unsigned)bf16rne(z3) << 16);
      const int off = (row << 9) + ((h0 * 2) ^ ((row & 15) << 4));
      *(unsigned*)((char*)s_h1 + off) = u0;
      *(unsigned*)((char*)s_h1 + off + 4) = u1;
    }
  }
  __syncthreads();

  // --- MFMA2 (+attn pool): waves 0..7, wave (wo=w&1, wn4=w>>1) ---
  if (w < 8) {
    const int wo = w & 1, wn4 = w >> 1;
    const int row = wn4 * 16 + lh;
    f32x4 acc2[4];
#pragma unroll
    for (int mt = 0; mt < 4; ++mt) acc2[mt] = (f32x4){0.f, 0.f, 0.f, 0.f};
#pragma unroll
    for (int ks = 0; ks < 8; ++ks) {
      const int off = (row << 9) + ((ks * 64 + kq * 16) ^ ((row & 15) << 4));
      const bf16x8 Bf = *(const bf16x8*)((const char*)s_h1 + off);
#pragma unroll
      for (int mt = 0; mt < 4; ++mt) {
        const bf16x8 Af = *(const bf16x8*)(
            We2T + (size_t)(wo * 64 + mt * 16 + lh) * 256 + ks * 32 + kq * 8);
        acc2[mt] = __builtin_amdgcn_mfma_f32_16x16x32_bf16(Af, Bf, acc2[mt], 0, 0, 0);
      }
    }
    const float at = s_at[row];
#pragma unroll
    for (int mt = 0; mt < 4; ++mt) {
#pragma unroll
      for (int j = 0; j < 4; ++j) {
        float v = acc2[mt][j] * at;
        v += __shfl_xor(v, 1);
        v += __shfl_xor(v, 2);
        v += __shfl_xor(v, 4);
        v += __shfl_xor(v, 8);
        if (lh == 0) red[wn4][wo * 64 + mt * 16 + kq * 4 + j] = v;
      }
    }
  }
  __syncthreads();

  // --- pool + LN ---
  float pooled = 0.0f;
  if (t < NO)
    pooled = red[0][t] + red[1][t] + red[2][t] + red[3][t] + be2[t];
  float s1 = (t < NO) ? pooled : 0.0f;
  float s2 = (t < NO) ? pooled * pooled : 0.0f;
#pragma unroll
  for (int off = 32; off >= 1; off >>= 1) {
    s1 += __shfl_xor(s1, off);
    s2 += __shfl_xor(s2, off);
  }
  if (t < NO && (t & 63) == 0) {
    rr[(t >> 6) * 2] = s1;
    rr[(t >> 6) * 2 + 1] = s2;
  }
  __syncthreads();
  if (t < NO) {
    const float S1 = rr[0] + rr[2];
    const float S2 = rr[1] + rr[3];
    const float mu = S1 / NO;
    const float var = S2 / NO - mu * mu;
    const float rs = rsqrtf(var + LN_EPS_F);
    out[(size_t)b * NO + t] = (pooled - mu) * rs * gamma[t] + beta[t];
  }
}

extern "C" void kernel_launch(void* const* d_in, const int* in_sizes, int n_in,
                              void* d_out, int out_size, void* d_ws, size_t ws_size,
                              hipStream_t stream) {
  (void)in_sizes; (void)n_in; (void)out_size; (void)ws_size;
  const float* seq = (const float*)d_in[0];
  const int* mask = (const int*)d_in[1];
  const float* tgt = (const float*)d_in[2];
  const float* pos = (const float*)d_in[3];
  const float* W1 = (const float*)d_in[4];
  const float* b1 = (const float*)d_in[5];
  const float* w2 = (const float*)d_in[6];
  const float* b2 = (const float*)d_in[7];
  const float* We1 = (const float*)d_in[8];
  const float* be1 = (const float*)d_in[9];
  const float* We2 = (const float*)d_in[10];
  const float* be2 = (const float*)d_in[11];
  const float* gam = (const float*)d_in[12];
  const float* bet = (const float*)d_in[13];
  float* out = (float*)d_out;

  float* P = (float*)d_ws;                            // NL*NH
  float* T = P + (size_t)NL * NH;                     // NB*NH
  float* scores = T + (size_t)NB * NH;                // NB*NL
  unsigned short* w1aT = (unsigned short*)(scores + (size_t)NB * NL);  // NH*ND
  unsigned short* we1T = w1aT + (size_t)NH * ND;      // 256*256
  unsigned short* we2T = we1T + (size_t)256 * 256;    // 128*256

  k_prep<<<ND + NL + NB + 512, 256, 0, stream>>>(W1, pos, tgt, b1, We1, We2,
                                                 w1aT, P, T, we1T, we2T);
  k_scores_mfma<<<dim3(NL / 128, NB / BLOOP), 512, 0, stream>>>(
      seq, mask, w1aT, w2, b2, b1, T, scores);
  k_tail<<<NB, 1024, 0, stream>>>(scores, seq, mask, W1, w2, b2, P, T, pos,
                                  we1T, be1, we2T, be2, gam, bet, out);
}

// Round 14
// 139.245 us; speedup vs baseline: 1.0474x; 1.0474x over previous
//
#include <hip/hip_runtime.h>
#include <hip/hip_bf16.h>

namespace {
constexpr int NB = 128;   // batch
constexpr int NL = 2048;  // seq len
constexpr int ND = 128;   // emb dim
constexpr int NH = 256;   // hidden
constexpr int NO = 128;   // encoder out dim
constexpr int NK = 64;    // top-k
constexpr int MCAP = 192; // candidate cap per batch
constexpr int HTHR = 96;  // histogram cumulative threshold
constexpr int BLOOP = 8;  // batches per score block
constexpr float MASK_FILL_F = -1e9f;
constexpr float LN_EPS_F = 1e-5f;
}

typedef __attribute__((ext_vector_type(8))) short bf16x8;
typedef __attribute__((ext_vector_type(4))) float f32x4;

__device__ __forceinline__ unsigned short bf16rne(float x) {
  unsigned u = __float_as_uint(x);
  return (unsigned short)((u + 0x7FFFu + ((u >> 16) & 1u)) >> 16);
}

// ---------- fused prep: W1aT | P | T | We1T | We2T ----------
__global__ __launch_bounds__(256) void k_prep(
    const float* __restrict__ W1, const float* __restrict__ pos,
    const float* __restrict__ tgt, const float* __restrict__ b1,
    const float* __restrict__ We1, const float* __restrict__ We2,
    unsigned short* __restrict__ W1aT, float* __restrict__ P,
    float* __restrict__ T, unsigned short* __restrict__ We1T,
    unsigned short* __restrict__ We2T) {
  const int blk = blockIdx.x, t = threadIdx.x;
  if (blk < ND) {  // W1aT[h][d]
    W1aT[(size_t)t * ND + blk] = bf16rne(W1[(size_t)blk * NH + t]);
    return;
  }
  if (blk >= ND + NL + NB) {
    const int b2 = blk - (ND + NL + NB);
    if (b2 < 256) {  // We1T[h][d]
      We1T[(size_t)t * 256 + b2] = bf16rne(We1[(size_t)b2 * NH + t]);
    } else {         // We2T[o][d]
      const int d = b2 - 256;
      if (t < NO) We2T[(size_t)t * 256 + d] = bf16rne(We2[(size_t)d * NO + t]);
    }
    return;
  }
  int r, w_off, add_bias;
  const float* src;
  float* out;
  if (blk < ND + NL) {
    r = blk - ND; src = pos; out = P; w_off = ND; add_bias = 1;
  } else {
    r = blk - (ND + NL); src = tgt; out = T; w_off = 2 * ND; add_bias = 0;
  }
  __shared__ float row[ND];
  if (t < ND) row[t] = src[(size_t)r * ND + t];
  __syncthreads();
  float acc = add_bias ? b1[t] : 0.0f;
#pragma unroll 8
  for (int d = 0; d < ND; ++d)
    acc = fmaf(row[d], W1[(size_t)(w_off + d) * NH + t], acc);
  out[(size_t)r * NH + t] = acc;
}

// ---------- approximate scores (validated config, unchanged) ----------
__global__ __launch_bounds__(512, 2) void k_scores_mfma(
    const float* __restrict__ seq, const int* __restrict__ mask,
    const unsigned short* __restrict__ W1aT, const float* __restrict__ w2,
    const float* __restrict__ b2, const float* __restrict__ b1,
    const float* __restrict__ T, float* __restrict__ scores) {
  const int l0 = blockIdx.x * 128;
  const int b0 = blockIdx.y * BLOOP;
  const int t = threadIdx.x;
  const int lane = t & 63;
  const int w = t >> 6;
  const int wh = w & 3;
  const int wl = w >> 2;
  const int lh = lane & 15;
  const int kq = lane >> 4;

  __shared__ unsigned short sSeq[2][128 * 128];
  __shared__ float sRed[4][128];

  bf16x8 a[4][4];
#pragma unroll
  for (int ks = 0; ks < 4; ++ks)
#pragma unroll
    for (int mt = 0; mt < 4; ++mt)
      a[ks][mt] = *(const bf16x8*)(
          W1aT + (size_t)(wh * 64 + mt * 16 + lh) * ND + ks * 32 + kq * 8);

  float4 wv[4], b1v[4];
#pragma unroll
  for (int mt = 0; mt < 4; ++mt) {
    wv[mt] = *(const float4*)(w2 + wh * 64 + mt * 16 + kq * 4);
    b1v[mt] = *(const float4*)(b1 + wh * 64 + mt * 16 + kq * 4);
  }
  const float b2v = b2[0];

  ushort4 pf[8];
  auto prefetch = [&](int bb) {
    const float4* g = (const float4*)(seq + ((size_t)bb * NL + l0) * ND);
#pragma unroll
    for (int i = 0; i < 8; ++i) {
      const float4 f = g[t + i * 512];
      pf[i].x = bf16rne(f.x); pf[i].y = bf16rne(f.y);
      pf[i].z = bf16rne(f.z); pf[i].w = bf16rne(f.w);
    }
  };
  auto commit = [&](unsigned short* dst) {
#pragma unroll
    for (int i = 0; i < 8; ++i) {
      const int v = t + i * 512;
      const int row = v >> 5;
      const int c8 = (v & 31) * 8;
      const int off = (row << 8) + (c8 ^ ((row & 15) << 4));
      *(ushort4*)((char*)dst + off) = pf[i];
    }
  };

  prefetch(b0);
  commit((unsigned short*)sSeq[0]);
  __syncthreads();

#pragma unroll 1
  for (int j = 0; j < BLOOP; ++j) {
    const int b = b0 + j;
    unsigned short* cSeq = (unsigned short*)sSeq[j & 1];
    unsigned short* nSeq = (unsigned short*)sSeq[(j & 1) ^ 1];

    if (j + 1 < BLOOP) prefetch(b + 1);

    float4 Tv[4];
#pragma unroll
    for (int mt = 0; mt < 4; ++mt)
      Tv[mt] = *(const float4*)(T + (size_t)b * NH + wh * 64 + mt * 16 + kq * 4);

    f32x4 acc[4][4];
#pragma unroll
    for (int mt = 0; mt < 4; ++mt)
#pragma unroll
      for (int nt = 0; nt < 4; ++nt) acc[mt][nt] = (f32x4){0.f, 0.f, 0.f, 0.f};

#pragma unroll
    for (int ks = 0; ks < 4; ++ks) {
      bf16x8 Bf[4];
#pragma unroll
      for (int nt = 0; nt < 4; ++nt) {
        const int row = wl * 64 + nt * 16 + lh;
        const int off = (row << 8) + (((ks << 6) + (kq << 4)) ^ ((row & 15) << 4));
        Bf[nt] = *(const bf16x8*)((const char*)cSeq + off);
      }
#pragma unroll
      for (int mt = 0; mt < 4; ++mt)
#pragma unroll
        for (int nt = 0; nt < 4; ++nt)
          acc[mt][nt] = __builtin_amdgcn_mfma_f32_16x16x32_bf16(
              a[ks][mt], Bf[nt], acc[mt][nt], 0, 0, 0);
    }
    __syncthreads();
    if (j + 1 < BLOOP) commit(nSeq);

    float p[4] = {0.f, 0.f, 0.f, 0.f};
#pragma unroll
    for (int mt = 0; mt < 4; ++mt) {
#pragma unroll
      for (int nt = 0; nt < 4; ++nt) {
        float z;
        z = acc[mt][nt][0] + Tv[mt].x + b1v[mt].x; p[nt] = fmaf(fmaxf(z, 0.f), wv[mt].x, p[nt]);
        z = acc[mt][nt][1] + Tv[mt].y + b1v[mt].y; p[nt] = fmaf(fmaxf(z, 0.f), wv[mt].y, p[nt]);
        z = acc[mt][nt][2] + Tv[mt].z + b1v[mt].z; p[nt] = fmaf(fmaxf(z, 0.f), wv[mt].z, p[nt]);
        z = acc[mt][nt][3] + Tv[mt].w + b1v[mt].w; p[nt] = fmaf(fmaxf(z, 0.f), wv[mt].w, p[nt]);
      }
    }
#pragma unroll
    for (int nt = 0; nt < 4; ++nt) {
      float v = p[nt];
      v += __shfl_xor(v, 16);
      v += __shfl_xor(v, 32);
      if (lane < 16) sRed[wh][wl * 64 + nt * 16 + lane] = v;
    }
    __syncthreads();
    if (t < 128) {
      const int l = l0 + t;
      float sc = sRed[0][t] + sRed[1][t] + sRed[2][t] + sRed[3][t] + b2v;
      if (mask[(size_t)b * NL + l] == 0) sc = MASK_FILL_F;
      scores[(size_t)b * NL + l] = sc;
    }
  }
}

// ---------- fused tail: topM + exact rescore + select + MFMA encoder + LN ----------
// one block per batch, 1024 threads (16 waves). Latency fixes vs R13:
// (1) parallel suffix-scan bin search (was 272-deep serial LDS chain ~14us),
// (2) pass-2 rescore skips waves beyond n (was full dead recompute),
// (3) unroll-2 d0 loop for memory-level parallelism.
__global__ __launch_bounds__(1024, 4) void k_tail(
    const float* __restrict__ scores, const float* __restrict__ seq,
    const int* __restrict__ mask, const float* __restrict__ W1,
    const float* __restrict__ w2, const float* __restrict__ b2,
    const float* __restrict__ P, const float* __restrict__ T,
    const float* __restrict__ pos,
    const unsigned short* __restrict__ We1T, const float* __restrict__ be1,
    const unsigned short* __restrict__ We2T, const float* __restrict__ be2,
    const float* __restrict__ gamma, const float* __restrict__ beta,
    float* __restrict__ out) {
  const int b = blockIdx.x, t = threadIdx.x;
  const int lane = t & 63, w = t >> 6;
  const int lh = lane & 15, kq = lane >> 4;
  __shared__ float s_stage[128 * ND];   // 64 KB; phase A aliases hist
  unsigned* hist = (unsigned*)s_stage;  // 4096 uints
  __shared__ unsigned chunk[256];
  __shared__ unsigned suf[257];
  __shared__ int sCsel, sBsel;
  __shared__ unsigned sCntHi, sCntB, sN;
  __shared__ int s_cand[MCAP];
  __shared__ float s_cs[MCAP];
  __shared__ unsigned long long s_key[MCAP];
  __shared__ int sel_l[NK];
  __shared__ float sel_v[NK];
  __shared__ int srt_l[NK];
  __shared__ float srt_v[NK];
  __shared__ float s_at[NK];
  __shared__ unsigned short s_in[64 * 256];  // 32 KB
  __shared__ unsigned short s_h1[64 * 256];  // 32 KB
  __shared__ float red[4][128];
  __shared__ float rr[4];

  // --- phase A: histogram (masked keys skipped; bit-identical selection) ---
  const unsigned mkey = ~__float_as_uint(MASK_FILL_F);
  for (int i = t; i < 4096; i += 1024) hist[i] = 0;
  if (t == 0) { sCntHi = 0; sCntB = 0; sCsel = 0; suf[256] = 0; }
  __syncthreads();
  unsigned key2[2];
#pragma unroll
  for (int i = 0; i < 2; ++i) {
    unsigned u = __float_as_uint(scores[(size_t)b * NL + t + i * 1024]);
    u = (u & 0x80000000u) ? ~u : (u | 0x80000000u);
    key2[i] = u;
    if (u != mkey) atomicAdd(&hist[u >> 20], 1u);
  }
  __syncthreads();
  if (t < 256) {
    unsigned s = 0;
#pragma unroll 4
    for (int j = 0; j < 16; ++j) s += hist[t * 16 + j];
    chunk[t] = s;
  }
  __syncthreads();
  // parallel suffix over 256 chunks; largest c with suf[c] >= HTHR
  if (t < 256) {
    unsigned s = 0;
    for (int j = t; j < 256; ++j) s += chunk[j];
    suf[t] = s;
    if (s >= (unsigned)HTHR) atomicMax(&sCsel, t);
  }
  __syncthreads();
  const int c = sCsel;
  if (t == 0) sBsel = c * 16;
  __syncthreads();
  if (t < 16) {
    unsigned s = 0;
    for (int j = c * 16 + t; j < c * 16 + 16; ++j) s += hist[j];
    if (s + suf[c + 1] >= (unsigned)HTHR) atomicMax(&sBsel, c * 16 + t);
  }
  __syncthreads();
  const unsigned B = (unsigned)sBsel;
#pragma unroll
  for (int i = 0; i < 2; ++i) {
    if (key2[i] != mkey && (key2[i] >> 20) > B) {
      unsigned pos_ = atomicAdd(&sCntHi, 1u);
      s_cand[pos_] = t + i * 1024;
    }
  }
  __syncthreads();
  const unsigned hi = sCntHi;
#pragma unroll
  for (int i = 0; i < 2; ++i) {
    if (key2[i] != mkey && (key2[i] >> 20) == B) {
      unsigned pos_ = atomicAdd(&sCntB, 1u);
      if (hi + pos_ < (unsigned)MCAP) s_cand[hi + pos_] = t + i * 1024;
    }
  }
  __syncthreads();
  if (t == 0) {
    unsigned n = sCntHi + sCntB;
    sN = (n < (unsigned)MCAP) ? n : (unsigned)MCAP;
  }
  __syncthreads();
  const int n = (int)sN;

  // --- phase B: exact fp32 rescore, 128 rows/pass staged in LDS ---
  {
    const int hg = lane;
    const int rg = w;
    const float4* Wp = (const float4*)W1;
    const float4 wvq = ((const float4*)w2)[hg];
    const float4 Tvq = ((const float4*)(T + (size_t)b * NH))[hg];
    const float b2v = b2[0];
#pragma unroll 1
    for (int pass = 0; pass < 2; ++pass) {
      const int base = pass * 128;
      if (base >= n) break;
      const int rows_here = (n - base < 128) ? (n - base) : 128;
      __syncthreads();
#pragma unroll
      for (int i = 0; i < 4; ++i) {
        const int v = t + i * 1024;
        const int r = v >> 5, cc = v & 31;
        if (r < rows_here) {
          ((float4*)s_stage)[r * 32 + cc] =
              ((const float4*)(seq + ((size_t)b * NL + s_cand[base + r]) * ND))[cc];
        }
      }
      __syncthreads();

      if (rg * 8 < rows_here) {  // wave-uniform: whole wave active or skipped
        float acc[8][4];
#pragma unroll
        for (int r = 0; r < 8; ++r)
#pragma unroll
          for (int j = 0; j < 4; ++j) acc[r][j] = 0.0f;

#pragma unroll 2
        for (int d0 = 0; d0 < ND; d0 += 4) {
          float4 wq[4];
#pragma unroll
          for (int j = 0; j < 4; ++j) wq[j] = Wp[(size_t)(d0 + j) * (NH / 4) + hg];
#pragma unroll
          for (int r = 0; r < 8; ++r) {
            const float4 s = *(const float4*)&s_stage[(rg * 8 + r) * ND + d0];
            const float sv[4] = {s.x, s.y, s.z, s.w};
#pragma unroll
            for (int j = 0; j < 4; ++j) {
              acc[r][0] = fmaf(sv[j], wq[j].x, acc[r][0]);
              acc[r][1] = fmaf(sv[j], wq[j].y, acc[r][1]);
              acc[r][2] = fmaf(sv[j], wq[j].z, acc[r][2]);
              acc[r][3] = fmaf(sv[j], wq[j].w, acc[r][3]);
            }
          }
        }

#pragma unroll
        for (int r = 0; r < 8; ++r) {
          const int slot = base + rg * 8 + r;
          const int l = (slot < n) ? s_cand[slot] : 0;
          const float4 Pv = ((const float4*)(P + (size_t)l * NH))[hg];
          float z, p = 0.0f;
          z = acc[r][0] + Pv.x + Tvq.x; p = fmaf(fmaxf(z, 0.0f), wvq.x, p);
          z = acc[r][1] + Pv.y + Tvq.y; p = fmaf(fmaxf(z, 0.0f), wvq.y, p);
          z = acc[r][2] + Pv.z + Tvq.z; p = fmaf(fmaxf(z, 0.0f), wvq.z, p);
          z = acc[r][3] + Pv.w + Tvq.w; p = fmaf(fmaxf(z, 0.0f), wvq.w, p);
#pragma unroll
          for (int off = 32; off >= 1; off >>= 1) p += __shfl_xor(p, off);
          if (hg == 0 && slot < n) {
            float sc = p + b2v;
            if (mask[(size_t)b * NL + l] == 0) sc = MASK_FILL_F;
            s_cs[slot] = sc;
          }
        }
      }
    }
  }
  __syncthreads();

  // --- phase C: rank-based exact top-64, index-sort, softmax (to LDS) ---
  for (int s = t; s < MCAP; s += 1024) {
    unsigned long long kk = 0ull;
    if (s < n) {
      unsigned u = __float_as_uint(s_cs[s]);
      u = (u & 0x80000000u) ? ~u : (u | 0x80000000u);
      const int l = s_cand[s];
      kk = ((unsigned long long)u << 11) | (unsigned long long)(NL - 1 - l);
    }
    s_key[s] = kk;
  }
  __syncthreads();
  for (int s = t; s < MCAP; s += 1024) {
    if (s < n) {
      const unsigned long long mk = s_key[s];
      int rank = 0;
      for (int j = 0; j < n; ++j) rank += (s_key[j] > mk) ? 1 : 0;
      if (rank < NK) {
        sel_l[rank] = (NL - 1) - (int)(mk & 0x7FFull);
        sel_v[rank] = s_cs[s];
      }
    }
  }
  __syncthreads();
  if (t < NK) {
    const int myl = sel_l[t];
    int pos_ = 0;
#pragma unroll 8
    for (int j = 0; j < NK; ++j) pos_ += (sel_l[j] < myl) ? 1 : 0;
    srt_l[pos_] = myl;
    srt_v[pos_] = sel_v[t];
  }
  __syncthreads();
  if (t < 64) {
    const float sc = srt_v[t];
    float m = sc;
#pragma unroll
    for (int off = 32; off >= 1; off >>= 1) m = fmaxf(m, __shfl_xor(m, off));
    const float e = expf(sc - m);
    float s = e;
#pragma unroll
    for (int off = 32; off >= 1; off >>= 1) s += __shfl_xor(s, off);
    s_at[t] = e / s;
  }
  __syncthreads();

  // --- gather [seq|pos] selected rows -> bf16 swizzled LDS ---
#pragma unroll
  for (int i = 0; i < 4; ++i) {
    const int v = t + i * 1024;  // 4096 ushort4
    const int row = v >> 6;      // 64 ushort4 per 512B row
    const int q = v & 63;
    const int idx = srt_l[row];
    float4 f;
    if (q < 32) f = ((const float4*)(seq + ((size_t)b * NL + idx) * ND))[q];
    else        f = ((const float4*)(pos + (size_t)idx * ND))[q - 32];
    ushort4 hv;
    hv.x = bf16rne(f.x); hv.y = bf16rne(f.y);
    hv.z = bf16rne(f.z); hv.w = bf16rne(f.w);
    const int off = (row << 9) + ((q * 8) ^ ((row & 15) << 4));
    *(ushort4*)((char*)s_in + off) = hv;
  }
  __syncthreads();

  // --- MFMA1: 16 waves, wave (wh=w&3, wn=w>>2) owns 64h x 16rows ---
  {
    const int wh = w & 3, wn = w >> 2;
    const int row = wn * 16 + lh;
    f32x4 acc1[4];
#pragma unroll
    for (int mt = 0; mt < 4; ++mt) acc1[mt] = (f32x4){0.f, 0.f, 0.f, 0.f};
#pragma unroll
    for (int ks = 0; ks < 8; ++ks) {
      const int off = (row << 9) + ((ks * 64 + kq * 16) ^ ((row & 15) << 4));
      const bf16x8 Bf = *(const bf16x8*)((const char*)s_in + off);
#pragma unroll
      for (int mt = 0; mt < 4; ++mt) {
        const bf16x8 Af = *(const bf16x8*)(
            We1T + (size_t)(wh * 64 + mt * 16 + lh) * 256 + ks * 32 + kq * 8);
        acc1[mt] = __builtin_amdgcn_mfma_f32_16x16x32_bf16(Af, Bf, acc1[mt], 0, 0, 0);
      }
    }
#pragma unroll
    for (int mt = 0; mt < 4; ++mt) {
      const int h0 = wh * 64 + mt * 16 + kq * 4;
      const float4 bv = *(const float4*)(be1 + h0);
      const float z0 = fmaxf(acc1[mt][0] + bv.x, 0.0f);
      const float z1 = fmaxf(acc1[mt][1] + bv.y, 0.0f);
      const float z2 = fmaxf(acc1[mt][2] + bv.z, 0.0f);
      const float z3 = fmaxf(acc1[mt][3] + bv.w, 0.0f);
      const unsigned u0 = (unsigned)bf16rne(z0) | ((unsigned)bf16rne(z1) << 16);
      const unsigned u1 = (unsigned)bf16rne(z2) | ((unsigned)bf16rne(z3) << 16);
      const int off = (row << 9) + ((h0 * 2) ^ ((row & 15) << 4));
      *(unsigned*)((char*)s_h1 + off) = u0;
      *(unsigned*)((char*)s_h1 + off + 4) = u1;
    }
  }
  __syncthreads();

  // --- MFMA2 (+attn pool): waves 0..7, wave (wo=w&1, wn4=w>>1) ---
  if (w < 8) {
    const int wo = w & 1, wn4 = w >> 1;
    const int row = wn4 * 16 + lh;
    f32x4 acc2[4];
#pragma unroll
    for (int mt = 0; mt < 4; ++mt) acc2[mt] = (f32x4){0.f, 0.f, 0.f, 0.f};
#pragma unroll
    for (int ks = 0; ks < 8; ++ks) {
      const int off = (row << 9) + ((ks * 64 + kq * 16) ^ ((row & 15) << 4));
      const bf16x8 Bf = *(const bf16x8*)((const char*)s_h1 + off);
#pragma unroll
      for (int mt = 0; mt < 4; ++mt) {
        const bf16x8 Af = *(const bf16x8*)(
            We2T + (size_t)(wo * 64 + mt * 16 + lh) * 256 + ks * 32 + kq * 8);
        acc2[mt] = __builtin_amdgcn_mfma_f32_16x16x32_bf16(Af, Bf, acc2[mt], 0, 0, 0);
      }
    }
    const float at = s_at[row];
#pragma unroll
    for (int mt = 0; mt < 4; ++mt) {
#pragma unroll
      for (int j = 0; j < 4; ++j) {
        float v = acc2[mt][j] * at;
        v += __shfl_xor(v, 1);
        v += __shfl_xor(v, 2);
        v += __shfl_xor(v, 4);
        v += __shfl_xor(v, 8);
        if (lh == 0) red[wn4][wo * 64 + mt * 16 + kq * 4 + j] = v;
      }
    }
  }
  __syncthreads();

  // --- pool + LN ---
  float pooled = 0.0f;
  if (t < NO)
    pooled = red[0][t] + red[1][t] + red[2][t] + red[3][t] + be2[t];
  float s1 = (t < NO) ? pooled : 0.0f;
  float s2 = (t < NO) ? pooled * pooled : 0.0f;
#pragma unroll
  for (int off = 32; off >= 1; off >>= 1) {
    s1 += __shfl_xor(s1, off);
    s2 += __shfl_xor(s2, off);
  }
  if (t < NO && (t & 63) == 0) {
    rr[(t >> 6) * 2] = s1;
    rr[(t >> 6) * 2 + 1] = s2;
  }
  __syncthreads();
  if (t < NO) {
    const float S1 = rr[0] + rr[2];
    const float S2 = rr[1] + rr[3];
    const float mu = S1 / NO;
    const float var = S2 / NO - mu * mu;
    const float rs = rsqrtf(var + LN_EPS_F);
    out[(size_t)b * NO + t] = (pooled - mu) * rs * gamma[t] + beta[t];
  }
}

extern "C" void kernel_launch(void* const* d_in, const int* in_sizes, int n_in,
                              void* d_out, int out_size, void* d_ws, size_t ws_size,
                              hipStream_t stream) {
  (void)in_sizes; (void)n_in; (void)out_size; (void)ws_size;
  const float* seq = (const float*)d_in[0];
  const int* mask = (const int*)d_in[1];
  const float* tgt = (const float*)d_in[2];
  const float* pos = (const float*)d_in[3];
  const float* W1 = (const float*)d_in[4];
  const float* b1 = (const float*)d_in[5];
  const float* w2 = (const float*)d_in[6];
  const float* b2 = (const float*)d_in[7];
  const float* We1 = (const float*)d_in[8];
  const float* be1 = (const float*)d_in[9];
  const float* We2 = (const float*)d_in[10];
  const float* be2 = (const float*)d_in[11];
  const float* gam = (const float*)d_in[12];
  const float* bet = (const float*)d_in[13];
  float* out = (float*)d_out;

  float* P = (float*)d_ws;                            // NL*NH
  float* T = P + (size_t)NL * NH;                     // NB*NH
  float* scores = T + (size_t)NB * NH;                // NB*NL
  unsigned short* w1aT = (unsigned short*)(scores + (size_t)NB * NL);  // NH*ND
  unsigned short* we1T = w1aT + (size_t)NH * ND;      // 256*256
  unsigned short* we2T = we1T + (size_t)256 * 256;    // 128*256

  k_prep<<<ND + NL + NB + 512, 256, 0, stream>>>(W1, pos, tgt, b1, We1, We2,
                                                 w1aT, P, T, we1T, we2T);
  k_scores_mfma<<<dim3(NL / 128, NB / BLOOP), 512, 0, stream>>>(
      seq, mask, w1aT, w2, b2, b1, T, scores);
  k_tail<<<NB, 1024, 0, stream>>>(scores, seq, mask, W1, w2, b2, P, T, pos,
                                  we1T, be1, we2T, be2, gam, bet, out);
}

// Round 15
// 116.491 us; speedup vs baseline: 1.2520x; 1.1953x over previous
//
#include <hip/hip_runtime.h>
#include <hip/hip_bf16.h>

namespace {
constexpr int NB = 128;   // batch
constexpr int NL = 2048;  // seq len
constexpr int ND = 128;   // emb dim
constexpr int NH = 256;   // hidden
constexpr int NO = 128;   // encoder out dim
constexpr int NK = 64;    // top-k
constexpr int MCAP = 192; // candidate cap per batch
constexpr int HTHR = 96;  // histogram cumulative threshold
constexpr int BLOOP = 8;  // batches per score block
constexpr float MASK_FILL_F = -1e9f;
constexpr float LN_EPS_F = 1e-5f;
}

typedef __attribute__((ext_vector_type(8))) short bf16x8;
typedef __attribute__((ext_vector_type(4))) float f32x4;

__device__ __forceinline__ unsigned short bf16rne(float x) {
  unsigned u = __float_as_uint(x);
  return (unsigned short)((u + 0x7FFFu + ((u >> 16) & 1u)) >> 16);
}

// ---------- fused prep: W1aT | P | T | We1T | We2T ----------
__global__ __launch_bounds__(256) void k_prep(
    const float* __restrict__ W1, const float* __restrict__ pos,
    const float* __restrict__ tgt, const float* __restrict__ b1,
    const float* __restrict__ We1, const float* __restrict__ We2,
    unsigned short* __restrict__ W1aT, float* __restrict__ P,
    float* __restrict__ T, unsigned short* __restrict__ We1T,
    unsigned short* __restrict__ We2T) {
  const int blk = blockIdx.x, t = threadIdx.x;
  if (blk < ND) {  // W1aT[h][d]
    W1aT[(size_t)t * ND + blk] = bf16rne(W1[(size_t)blk * NH + t]);
    return;
  }
  if (blk >= ND + NL + NB) {
    const int b2 = blk - (ND + NL + NB);
    if (b2 < 256) {  // We1T[h][d]
      We1T[(size_t)t * 256 + b2] = bf16rne(We1[(size_t)b2 * NH + t]);
    } else {         // We2T[o][d]
      const int d = b2 - 256;
      if (t < NO) We2T[(size_t)t * 256 + d] = bf16rne(We2[(size_t)d * NO + t]);
    }
    return;
  }
  int r, w_off, add_bias;
  const float* src;
  float* out;
  if (blk < ND + NL) {
    r = blk - ND; src = pos; out = P; w_off = ND; add_bias = 1;
  } else {
    r = blk - (ND + NL); src = tgt; out = T; w_off = 2 * ND; add_bias = 0;
  }
  __shared__ float row[ND];
  if (t < ND) row[t] = src[(size_t)r * ND + t];
  __syncthreads();
  float acc = add_bias ? b1[t] : 0.0f;
#pragma unroll 8
  for (int d = 0; d < ND; ++d)
    acc = fmaf(row[d], W1[(size_t)(w_off + d) * NH + t], acc);
  out[(size_t)r * NH + t] = acc;
}

// ---------- approximate scores (validated config, unchanged) ----------
__global__ __launch_bounds__(512, 2) void k_scores_mfma(
    const float* __restrict__ seq, const int* __restrict__ mask,
    const unsigned short* __restrict__ W1aT, const float* __restrict__ w2,
    const float* __restrict__ b2, const float* __restrict__ b1,
    const float* __restrict__ T, float* __restrict__ scores) {
  const int l0 = blockIdx.x * 128;
  const int b0 = blockIdx.y * BLOOP;
  const int t = threadIdx.x;
  const int lane = t & 63;
  const int w = t >> 6;
  const int wh = w & 3;
  const int wl = w >> 2;
  const int lh = lane & 15;
  const int kq = lane >> 4;

  __shared__ unsigned short sSeq[2][128 * 128];
  __shared__ float sRed[4][128];

  bf16x8 a[4][4];
#pragma unroll
  for (int ks = 0; ks < 4; ++ks)
#pragma unroll
    for (int mt = 0; mt < 4; ++mt)
      a[ks][mt] = *(const bf16x8*)(
          W1aT + (size_t)(wh * 64 + mt * 16 + lh) * ND + ks * 32 + kq * 8);

  float4 wv[4], b1v[4];
#pragma unroll
  for (int mt = 0; mt < 4; ++mt) {
    wv[mt] = *(const float4*)(w2 + wh * 64 + mt * 16 + kq * 4);
    b1v[mt] = *(const float4*)(b1 + wh * 64 + mt * 16 + kq * 4);
  }
  const float b2v = b2[0];

  ushort4 pf[8];
  auto prefetch = [&](int bb) {
    const float4* g = (const float4*)(seq + ((size_t)bb * NL + l0) * ND);
#pragma unroll
    for (int i = 0; i < 8; ++i) {
      const float4 f = g[t + i * 512];
      pf[i].x = bf16rne(f.x); pf[i].y = bf16rne(f.y);
      pf[i].z = bf16rne(f.z); pf[i].w = bf16rne(f.w);
    }
  };
  auto commit = [&](unsigned short* dst) {
#pragma unroll
    for (int i = 0; i < 8; ++i) {
      const int v = t + i * 512;
      const int row = v >> 5;
      const int c8 = (v & 31) * 8;
      const int off = (row << 8) + (c8 ^ ((row & 15) << 4));
      *(ushort4*)((char*)dst + off) = pf[i];
    }
  };

  prefetch(b0);
  commit((unsigned short*)sSeq[0]);
  __syncthreads();

#pragma unroll 1
  for (int j = 0; j < BLOOP; ++j) {
    const int b = b0 + j;
    unsigned short* cSeq = (unsigned short*)sSeq[j & 1];
    unsigned short* nSeq = (unsigned short*)sSeq[(j & 1) ^ 1];

    if (j + 1 < BLOOP) prefetch(b + 1);

    float4 Tv[4];
#pragma unroll
    for (int mt = 0; mt < 4; ++mt)
      Tv[mt] = *(const float4*)(T + (size_t)b * NH + wh * 64 + mt * 16 + kq * 4);

    f32x4 acc[4][4];
#pragma unroll
    for (int mt = 0; mt < 4; ++mt)
#pragma unroll
      for (int nt = 0; nt < 4; ++nt) acc[mt][nt] = (f32x4){0.f, 0.f, 0.f, 0.f};

#pragma unroll
    for (int ks = 0; ks < 4; ++ks) {
      bf16x8 Bf[4];
#pragma unroll
      for (int nt = 0; nt < 4; ++nt) {
        const int row = wl * 64 + nt * 16 + lh;
        const int off = (row << 8) + (((ks << 6) + (kq << 4)) ^ ((row & 15) << 4));
        Bf[nt] = *(const bf16x8*)((const char*)cSeq + off);
      }
#pragma unroll
      for (int mt = 0; mt < 4; ++mt)
#pragma unroll
        for (int nt = 0; nt < 4; ++nt)
          acc[mt][nt] = __builtin_amdgcn_mfma_f32_16x16x32_bf16(
              a[ks][mt], Bf[nt], acc[mt][nt], 0, 0, 0);
    }
    __syncthreads();
    if (j + 1 < BLOOP) commit(nSeq);

    float p[4] = {0.f, 0.f, 0.f, 0.f};
#pragma unroll
    for (int mt = 0; mt < 4; ++mt) {
#pragma unroll
      for (int nt = 0; nt < 4; ++nt) {
        float z;
        z = acc[mt][nt][0] + Tv[mt].x + b1v[mt].x; p[nt] = fmaf(fmaxf(z, 0.f), wv[mt].x, p[nt]);
        z = acc[mt][nt][1] + Tv[mt].y + b1v[mt].y; p[nt] = fmaf(fmaxf(z, 0.f), wv[mt].y, p[nt]);
        z = acc[mt][nt][2] + Tv[mt].z + b1v[mt].z; p[nt] = fmaf(fmaxf(z, 0.f), wv[mt].z, p[nt]);
        z = acc[mt][nt][3] + Tv[mt].w + b1v[mt].w; p[nt] = fmaf(fmaxf(z, 0.f), wv[mt].w, p[nt]);
      }
    }
#pragma unroll
    for (int nt = 0; nt < 4; ++nt) {
      float v = p[nt];
      v += __shfl_xor(v, 16);
      v += __shfl_xor(v, 32);
      if (lane < 16) sRed[wh][wl * 64 + nt * 16 + lane] = v;
    }
    __syncthreads();
    if (t < 128) {
      const int l = l0 + t;
      float sc = sRed[0][t] + sRed[1][t] + sRed[2][t] + sRed[3][t] + b2v;
      if (mask[(size_t)b * NL + l] == 0) sc = MASK_FILL_F;
      scores[(size_t)b * NL + l] = sc;
    }
  }
}

// ---------- phase A: histogram topM candidate selection (per batch) ----------
__global__ __launch_bounds__(1024, 4) void k_topA(
    const float* __restrict__ scores, int* __restrict__ cand_idx,
    int* __restrict__ cand_n) {
  const int b = blockIdx.x, t = threadIdx.x;
  __shared__ unsigned hist[4096];
  __shared__ unsigned chunk[256];
  __shared__ unsigned suf[257];
  __shared__ int sCsel, sBsel;
  __shared__ unsigned sCntHi, sCntB;
  __shared__ int s_cand[MCAP];

  const unsigned mkey = ~__float_as_uint(MASK_FILL_F);
  for (int i = t; i < 4096; i += 1024) hist[i] = 0;
  if (t == 0) { sCntHi = 0; sCntB = 0; sCsel = 0; suf[256] = 0; }
  __syncthreads();
  unsigned key2[2];
#pragma unroll
  for (int i = 0; i < 2; ++i) {
    unsigned u = __float_as_uint(scores[(size_t)b * NL + t + i * 1024]);
    u = (u & 0x80000000u) ? ~u : (u | 0x80000000u);
    key2[i] = u;
    if (u != mkey) atomicAdd(&hist[u >> 20], 1u);
  }
  __syncthreads();
  if (t < 256) {
    unsigned s = 0;
#pragma unroll 4
    for (int j = 0; j < 16; ++j) s += hist[t * 16 + j];
    chunk[t] = s;
  }
  __syncthreads();
  if (t < 256) {
    unsigned s = 0;
    for (int j = t; j < 256; ++j) s += chunk[j];
    suf[t] = s;
    if (s >= (unsigned)HTHR) atomicMax(&sCsel, t);
  }
  __syncthreads();
  const int c = sCsel;
  if (t == 0) sBsel = c * 16;
  __syncthreads();
  if (t < 16) {
    unsigned s = 0;
    for (int j = c * 16 + t; j < c * 16 + 16; ++j) s += hist[j];
    if (s + suf[c + 1] >= (unsigned)HTHR) atomicMax(&sBsel, c * 16 + t);
  }
  __syncthreads();
  const unsigned B = (unsigned)sBsel;
#pragma unroll
  for (int i = 0; i < 2; ++i) {
    if (key2[i] != mkey && (key2[i] >> 20) > B) {
      unsigned pos_ = atomicAdd(&sCntHi, 1u);
      s_cand[pos_] = t + i * 1024;
    }
  }
  __syncthreads();
  const unsigned hi = sCntHi;
#pragma unroll
  for (int i = 0; i < 2; ++i) {
    if (key2[i] != mkey && (key2[i] >> 20) == B) {
      unsigned pos_ = atomicAdd(&sCntB, 1u);
      if (hi + pos_ < (unsigned)MCAP) s_cand[hi + pos_] = t + i * 1024;
    }
  }
  __syncthreads();
  unsigned n = sCntHi + sCntB;
  if (n > (unsigned)MCAP) n = MCAP;
  if (t < MCAP) cand_idx[(size_t)b * MCAP + t] = (t < (int)n) ? s_cand[t] : 0;
  if (t == 0) cand_n[b] = (int)n;
}

// ---------- wide exact fp32 rescore (R9-proven shape: 768 blocks, 32 rows) ----------
__global__ __launch_bounds__(256) void k_rescoreW(
    const float* __restrict__ seq, const int* __restrict__ mask,
    const float* __restrict__ W1, const float* __restrict__ w2,
    const float* __restrict__ b2, const float* __restrict__ P,
    const float* __restrict__ T, const int* __restrict__ cand_idx,
    const int* __restrict__ cand_n, float* __restrict__ cscore) {
  const int b = blockIdx.y;
  const int s0 = blockIdx.x * 32;
  const int n = cand_n[b];
  if (s0 >= n) return;
  const int t = threadIdx.x;
  __shared__ float s_seq[32 * 128];
  __shared__ int s_l[32];
  if (t < 32) {
    const int slot = s0 + t;
    s_l[t] = (slot < n) ? cand_idx[(size_t)b * MCAP + slot] : 0;
  }
  __syncthreads();
#pragma unroll
  for (int i = 0; i < 4; ++i) {
    const int v = t + i * 256;
    const int r = v >> 5, c = v & 31;
    ((float4*)s_seq)[r * 32 + c] =
        ((const float4*)(seq + ((size_t)b * NL + s_l[r]) * ND))[c];
  }
  __syncthreads();

  const int hg = t & 63, rg = t >> 6;
  float acc[8][4];
#pragma unroll
  for (int r = 0; r < 8; ++r)
#pragma unroll
    for (int j = 0; j < 4; ++j) acc[r][j] = 0.0f;

  const float4* Wp = (const float4*)W1;
  for (int d0 = 0; d0 < ND; d0 += 4) {
    float4 wq[4];
#pragma unroll
    for (int j = 0; j < 4; ++j) wq[j] = Wp[(size_t)(d0 + j) * (NH / 4) + hg];
#pragma unroll
    for (int r = 0; r < 8; ++r) {
      const float4 s = *(const float4*)&s_seq[(rg * 8 + r) * ND + d0];
      const float sv[4] = {s.x, s.y, s.z, s.w};
#pragma unroll
      for (int j = 0; j < 4; ++j) {
        acc[r][0] = fmaf(sv[j], wq[j].x, acc[r][0]);
        acc[r][1] = fmaf(sv[j], wq[j].y, acc[r][1]);
        acc[r][2] = fmaf(sv[j], wq[j].z, acc[r][2]);
        acc[r][3] = fmaf(sv[j], wq[j].w, acc[r][3]);
      }
    }
  }

  const float4 wv = ((const float4*)w2)[hg];
  const float4 Tv = ((const float4*)(T + (size_t)b * NH))[hg];
  const float b2v = b2[0];
#pragma unroll
  for (int r = 0; r < 8; ++r) {
    const int l = s_l[rg * 8 + r];
    const float4 Pv = ((const float4*)(P + (size_t)l * NH))[hg];
    float z, p = 0.0f;
    z = acc[r][0] + Pv.x + Tv.x; p = fmaf(fmaxf(z, 0.0f), wv.x, p);
    z = acc[r][1] + Pv.y + Tv.y; p = fmaf(fmaxf(z, 0.0f), wv.y, p);
    z = acc[r][2] + Pv.z + Tv.z; p = fmaf(fmaxf(z, 0.0f), wv.z, p);
    z = acc[r][3] + Pv.w + Tv.w; p = fmaf(fmaxf(z, 0.0f), wv.w, p);
#pragma unroll
    for (int off = 32; off >= 1; off >>= 1) p += __shfl_xor(p, off);
    if (hg == 0) {
      float sc = p + b2v;
      if (mask[(size_t)b * NL + l] == 0) sc = MASK_FILL_F;
      cscore[(size_t)b * MCAP + s0 + rg * 8 + r] = sc;
    }
  }
}

// ---------- phase C + MFMA encoder + LN (per batch, 512 thr, ~70KB LDS) ----------
__global__ __launch_bounds__(512, 2) void k_selenc(
    const float* __restrict__ cscore, const int* __restrict__ cand_idx,
    const int* __restrict__ cand_n, const float* __restrict__ seq,
    const float* __restrict__ pos,
    const unsigned short* __restrict__ We1T, const float* __restrict__ be1,
    const unsigned short* __restrict__ We2T, const float* __restrict__ be2,
    const float* __restrict__ gamma, const float* __restrict__ beta,
    float* __restrict__ out) {
  const int b = blockIdx.x, t = threadIdx.x;
  const int lane = t & 63, w = t >> 6;
  const int lh = lane & 15, kq = lane >> 4;
  __shared__ unsigned long long s_key[MCAP];
  __shared__ float s_cs[MCAP];
  __shared__ int sel_l[NK];
  __shared__ float sel_v[NK];
  __shared__ int srt_l[NK];
  __shared__ float srt_v[NK];
  __shared__ float s_at[NK];
  __shared__ unsigned short s_in[64 * 256];  // 32 KB
  __shared__ unsigned short s_h1[64 * 256];  // 32 KB
  __shared__ float red[4][128];
  __shared__ float rr[4];

  const int n = cand_n[b];
  for (int s = t; s < MCAP; s += 512) {
    unsigned long long kk = 0ull;
    float f = 0.0f;
    if (s < n) {
      f = cscore[(size_t)b * MCAP + s];
      unsigned u = __float_as_uint(f);
      u = (u & 0x80000000u) ? ~u : (u | 0x80000000u);
      const int l = cand_idx[(size_t)b * MCAP + s];
      kk = ((unsigned long long)u << 11) | (unsigned long long)(NL - 1 - l);
    }
    s_key[s] = kk;
    s_cs[s] = f;
  }
  __syncthreads();
  for (int s = t; s < MCAP; s += 512) {
    if (s < n) {
      const unsigned long long mk = s_key[s];
      int rank = 0;
      for (int j = 0; j < n; ++j) rank += (s_key[j] > mk) ? 1 : 0;
      if (rank < NK) {
        sel_l[rank] = (NL - 1) - (int)(mk & 0x7FFull);
        sel_v[rank] = s_cs[s];
      }
    }
  }
  __syncthreads();
  if (t < NK) {
    const int myl = sel_l[t];
    int pos_ = 0;
#pragma unroll 8
    for (int j = 0; j < NK; ++j) pos_ += (sel_l[j] < myl) ? 1 : 0;
    srt_l[pos_] = myl;
    srt_v[pos_] = sel_v[t];
  }
  __syncthreads();
  if (t < 64) {
    const float sc = srt_v[t];
    float m = sc;
#pragma unroll
    for (int off = 32; off >= 1; off >>= 1) m = fmaxf(m, __shfl_xor(m, off));
    const float e = expf(sc - m);
    float s = e;
#pragma unroll
    for (int off = 32; off >= 1; off >>= 1) s += __shfl_xor(s, off);
    s_at[t] = e / s;
  }
  __syncthreads();

  // gather [seq|pos] selected rows -> bf16 swizzled LDS
#pragma unroll
  for (int i = 0; i < 8; ++i) {
    const int v = t + i * 512;   // 4096 ushort4
    const int row = v >> 6;
    const int q = v & 63;
    const int idx = srt_l[row];
    float4 f;
    if (q < 32) f = ((const float4*)(seq + ((size_t)b * NL + idx) * ND))[q];
    else        f = ((const float4*)(pos + (size_t)idx * ND))[q - 32];
    ushort4 hv;
    hv.x = bf16rne(f.x); hv.y = bf16rne(f.y);
    hv.z = bf16rne(f.z); hv.w = bf16rne(f.w);
    const int off = (row << 9) + ((q * 8) ^ ((row & 15) << 4));
    *(ushort4*)((char*)s_in + off) = hv;
  }
  __syncthreads();

  // MFMA1: 8 waves, wave (wh=w&3, wn=w>>2) owns 64h x 32rows
  {
    const int wh = w & 3, wn = w >> 2;
    f32x4 acc1[4][2];
#pragma unroll
    for (int mt = 0; mt < 4; ++mt)
#pragma unroll
      for (int nt = 0; nt < 2; ++nt) acc1[mt][nt] = (f32x4){0.f, 0.f, 0.f, 0.f};
#pragma unroll
    for (int ks = 0; ks < 8; ++ks) {
      bf16x8 Bf[2];
#pragma unroll
      for (int nt = 0; nt < 2; ++nt) {
        const int row = wn * 32 + nt * 16 + lh;
        const int off = (row << 9) + ((ks * 64 + kq * 16) ^ ((row & 15) << 4));
        Bf[nt] = *(const bf16x8*)((const char*)s_in + off);
      }
#pragma unroll
      for (int mt = 0; mt < 4; ++mt) {
        const bf16x8 Af = *(const bf16x8*)(
            We1T + (size_t)(wh * 64 + mt * 16 + lh) * 256 + ks * 32 + kq * 8);
#pragma unroll
        for (int nt = 0; nt < 2; ++nt)
          acc1[mt][nt] = __builtin_amdgcn_mfma_f32_16x16x32_bf16(
              Af, Bf[nt], acc1[mt][nt], 0, 0, 0);
      }
    }
#pragma unroll
    for (int mt = 0; mt < 4; ++mt) {
      const int h0 = wh * 64 + mt * 16 + kq * 4;
      const float4 bv = *(const float4*)(be1 + h0);
#pragma unroll
      for (int nt = 0; nt < 2; ++nt) {
        const int row = wn * 32 + nt * 16 + lh;
        const float z0 = fmaxf(acc1[mt][nt][0] + bv.x, 0.0f);
        const float z1 = fmaxf(acc1[mt][nt][1] + bv.y, 0.0f);
        const float z2 = fmaxf(acc1[mt][nt][2] + bv.z, 0.0f);
        const float z3 = fmaxf(acc1[mt][nt][3] + bv.w, 0.0f);
        const unsigned u0 = (unsigned)bf16rne(z0) | ((unsigned)bf16rne(z1) << 16);
        const unsigned u1 = (unsigned)bf16rne(z2) | ((unsigned)bf16rne(z3) << 16);
        const int off = (row << 9) + ((h0 * 2) ^ ((row & 15) << 4));
        *(unsigned*)((char*)s_h1 + off) = u0;
        *(unsigned*)((char*)s_h1 + off + 4) = u1;
      }
    }
  }
  __syncthreads();

  // MFMA2 (+attn pool): 8 waves, wave (wo=w&1, wn4=w>>1)
  {
    const int wo = w & 1, wn4 = w >> 1;
    const int row = wn4 * 16 + lh;
    f32x4 acc2[4];
#pragma unroll
    for (int mt = 0; mt < 4; ++mt) acc2[mt] = (f32x4){0.f, 0.f, 0.f, 0.f};
#pragma unroll
    for (int ks = 0; ks < 8; ++ks) {
      const int off = (row << 9) + ((ks * 64 + kq * 16) ^ ((row & 15) << 4));
      const bf16x8 Bf = *(const bf16x8*)((const char*)s_h1 + off);
#pragma unroll
      for (int mt = 0; mt < 4; ++mt) {
        const bf16x8 Af = *(const bf16x8*)(
            We2T + (size_t)(wo * 64 + mt * 16 + lh) * 256 + ks * 32 + kq * 8);
        acc2[mt] = __builtin_amdgcn_mfma_f32_16x16x32_bf16(Af, Bf, acc2[mt], 0, 0, 0);
      }
    }
    const float at = s_at[row];
#pragma unroll
    for (int mt = 0; mt < 4; ++mt) {
#pragma unroll
      for (int j = 0; j < 4; ++j) {
        float v = acc2[mt][j] * at;
        v += __shfl_xor(v, 1);
        v += __shfl_xor(v, 2);
        v += __shfl_xor(v, 4);
        v += __shfl_xor(v, 8);
        if (lh == 0) red[wn4][wo * 64 + mt * 16 + kq * 4 + j] = v;
      }
    }
  }
  __syncthreads();

  // pool + LN
  float pooled = 0.0f;
  if (t < NO)
    pooled = red[0][t] + red[1][t] + red[2][t] + red[3][t] + be2[t];
  float s1 = (t < NO) ? pooled : 0.0f;
  float s2 = (t < NO) ? pooled * pooled : 0.0f;
#pragma unroll
  for (int off = 32; off >= 1; off >>= 1) {
    s1 += __shfl_xor(s1, off);
    s2 += __shfl_xor(s2, off);
  }
  if (t < NO && (t & 63) == 0) {
    rr[(t >> 6) * 2] = s1;
    rr[(t >> 6) * 2 + 1] = s2;
  }
  __syncthreads();
  if (t < NO) {
    const float S1 = rr[0] + rr[2];
    const float S2 = rr[1] + rr[3];
    const float mu = S1 / NO;
    const float var = S2 / NO - mu * mu;
    const float rs = rsqrtf(var + LN_EPS_F);
    out[(size_t)b * NO + t] = (pooled - mu) * rs * gamma[t] + beta[t];
  }
}

extern "C" void kernel_launch(void* const* d_in, const int* in_sizes, int n_in,
                              void* d_out, int out_size, void* d_ws, size_t ws_size,
                              hipStream_t stream) {
  (void)in_sizes; (void)n_in; (void)out_size; (void)ws_size;
  const float* seq = (const float*)d_in[0];
  const int* mask = (const int*)d_in[1];
  const float* tgt = (const float*)d_in[2];
  const float* pos = (const float*)d_in[3];
  const float* W1 = (const float*)d_in[4];
  const float* b1 = (const float*)d_in[5];
  const float* w2 = (const float*)d_in[6];
  const float* b2 = (const float*)d_in[7];
  const float* We1 = (const float*)d_in[8];
  const float* be1 = (const float*)d_in[9];
  const float* We2 = (const float*)d_in[10];
  const float* be2 = (const float*)d_in[11];
  const float* gam = (const float*)d_in[12];
  const float* bet = (const float*)d_in[13];
  float* out = (float*)d_out;

  float* P = (float*)d_ws;                            // NL*NH
  float* T = P + (size_t)NL * NH;                     // NB*NH
  float* scores = T + (size_t)NB * NH;                // NB*NL
  unsigned short* w1aT = (unsigned short*)(scores + (size_t)NB * NL);  // NH*ND
  unsigned short* we1T = w1aT + (size_t)NH * ND;      // 256*256
  unsigned short* we2T = we1T + (size_t)256 * 256;    // 128*256
  int* cand_idx = (int*)(we2T + (size_t)128 * 256);   // NB*MCAP
  int* cand_n = cand_idx + (size_t)NB * MCAP;         // NB
  float* cscore = (float*)(cand_n + NB);              // NB*MCAP

  k_prep<<<ND + NL + NB + 512, 256, 0, stream>>>(W1, pos, tgt, b1, We1, We2,
                                                 w1aT, P, T, we1T, we2T);
  k_scores_mfma<<<dim3(NL / 128, NB / BLOOP), 512, 0, stream>>>(
      seq, mask, w1aT, w2, b2, b1, T, scores);
  k_topA<<<NB, 1024, 0, stream>>>(scores, cand_idx, cand_n);
  k_rescoreW<<<dim3(MCAP / 32, NB), 256, 0, stream>>>(
      seq, mask, W1, w2, b2, P, T, cand_idx, cand_n, cscore);
  k_selenc<<<NB, 512, 0, stream>>>(cscore, cand_idx, cand_n, seq, pos,
                                   we1T, be1, we2T, be2, gam, bet, out);
}